// Round 10
// baseline (172598.535 us; speedup 1.0000x reference)
//
#include <hip/hip_runtime.h>
#include <math.h>

#define FIN   32
#define HH    512
#define G4    2048
#define BNE   64
#define OUTD  8
#define SEQL  128
#define LOOK  32
#define TOT   (SEQL + LOOK)
#define GS    32              // samples per 4-WG group
#define NTHR  1024
#define NWG   256

// ---- workspace layout (float indices) — identical to r4 ----
#define ST_SZ   (64 * HH * GS)                 // one state array, all 64 groups
#define WS_ST   1024                            // 4KB of group counters first
#define WS_H0D  (WS_ST + 4 * ST_SZ)
#define WS_H1D  (WS_H0D + ST_SZ)
#define WS_TR   (WS_H1D + ST_SZ)                // trits [64][2][64][32]
#define WS_SOUT (WS_TR + 64 * 2 * BNE * GS)     // sout  [64][32][8]

__device__ __forceinline__ float sigf(float v) { return 1.0f / (1.0f + expf(-v)); }

// 4-WG group barrier: monotonic counter, device-scope (r4-proven protocol)
__device__ __forceinline__ void gbar(int* cnt, int target) {
  __syncthreads();
  if (threadIdx.x == 0) {
    __hip_atomic_fetch_add(cnt, 1, __ATOMIC_ACQ_REL, __HIP_MEMORY_SCOPE_AGENT);
    while (__hip_atomic_load(cnt, __ATOMIC_ACQUIRE, __HIP_MEMORY_SCOPE_AGENT) < target)
      __builtin_amdgcn_s_sleep(4);
  }
  __syncthreads();
  __threadfence();
}

// acc a[si] (float2 over col-pair) += hs * w  for 8 samples (r4 verbatim)
#define MACQ(HA, HB)                                            \
  { a[0].x = fmaf(w.x, HA.x, a[0].x); a[0].y = fmaf(w.y, HA.x, a[0].y); \
    a[1].x = fmaf(w.x, HA.y, a[1].x); a[1].y = fmaf(w.y, HA.y, a[1].y); \
    a[2].x = fmaf(w.x, HA.z, a[2].x); a[2].y = fmaf(w.y, HA.z, a[2].y); \
    a[3].x = fmaf(w.x, HA.w, a[3].x); a[3].y = fmaf(w.y, HA.w, a[3].y); \
    a[4].x = fmaf(w.x, HB.x, a[4].x); a[4].y = fmaf(w.y, HB.x, a[4].y); \
    a[5].x = fmaf(w.x, HB.y, a[5].x); a[5].y = fmaf(w.y, HB.y, a[5].y); \
    a[6].x = fmaf(w.x, HB.z, a[6].x); a[6].y = fmaf(w.y, HB.z, a[6].y); \
    a[7].x = fmaf(w.x, HB.w, a[7].x); a[7].y = fmaf(w.y, HB.w, a[7].y); }

__global__ __launch_bounds__(NTHR)
void fused_rnn(const float* __restrict__ x,
               const float* __restrict__ Wih0, const float* __restrict__ Whh0,
               const float* __restrict__ bih0, const float* __restrict__ bhh0,
               const float* __restrict__ Wih1, const float* __restrict__ Whh1,
               const float* __restrict__ bih1, const float* __restrict__ bhh1,
               const float* __restrict__ We,   const float* __restrict__ be,
               const float* __restrict__ Wd,   const float* __restrict__ bd,
               const float* __restrict__ Wf,   const float* __restrict__ bf,
               float* __restrict__ out, float* __restrict__ ws)
{
  // 64 KB time-shared arena:
  //   P1: encoder states [512][32] = [k][a*8+se], a in {h0,c0,h1,c1}
  //   P3: h0d [512][32], then gates [32][512]
  //   P4: h0c [512][32], then h1d [512][32], then gates [32][512]
  __shared__ float arena[HH * GS];
  __shared__ float tq[2][BNE][GS];        // 16 KB trits; sxT overlays tq[0] in P3
  __shared__ float cd[2][128][GS + 1];    // 33 KB decoded-c quarters (padded)

#define AK(K, S) arena[(K) * GS + (S)]
#define GB(S, C) arena[(S) * HH + (C)]

  const int t   = threadIdx.x;
  const int bid = blockIdx.x;
  const int G   = bid & 63;               // group
  const int Q   = bid >> 6;               // quarter 0..3
  const int S0  = G * GS;                 // first global sample of group
  const int UQ  = Q * 128;                // unit-quarter base

  int*   cnt = (int*)ws + G * 16;
  float* h0c = ws + WS_ST + 0 * ST_SZ + G * (HH * GS);
  float* c0c = ws + WS_ST + 1 * ST_SZ + G * (HH * GS);
  float* h1c = ws + WS_ST + 2 * ST_SZ + G * (HH * GS);
  float* c1c = ws + WS_ST + 3 * ST_SZ + G * (HH * GS);
  float* h0d = ws + WS_H0D + G * (HH * GS);
  float* h1d = ws + WS_H1D + G * (HH * GS);
  float* trg = ws + WS_TR  + G * (2 * BNE * GS);
  float* sog = ws + WS_SOUT + G * (GS * OUTD);

  // ---- matmul mapping (r4 verbatim): wave (p, v); lane wl owns col pair ----
  const int u = t & 255, v = t >> 8;      // v: sample block (8 samples)
  const int p = u >> 6, wl = u & 63;      // gate panel, col-pair lane
  const int cg = p * HH + UQ + 2 * wl;    // global gate column (even)
  const float2 bb0 = make_float2(bih0[cg] + bhh0[cg], bih0[cg + 1] + bhh0[cg + 1]);
  const float2 bb1 = make_float2(bih1[cg] + bhh1[cg], bih1[cg + 1] + bhh1[cg + 1]);

  // ---- decode mapping (r4 verbatim) ----
  const int cl = t & 255, sg2 = t >> 8;   // col-local, sample block
  const int dcol = (cl < 128) ? (UQ + cl) : (HH + UQ + (cl - 128));
  const float bdv = bd[dcol];

  // ---- encoder mapping (r4 verbatim): WG handles group-samples [8Q, 8Q+8) ----
  const int ae = t >> 9, se = (t >> 6) & 7, n = t & 63;
  const int sE = 8 * Q + se;

  // ---- elementwise mapping (r4 verbatim) ----
  const int ul = t & 127, sq8 = t >> 7;

  const double Athr = 0.5493061443340549; // atanh(0.5)

  int bar = 0;

  for (int step = 0; step < TOT; ++step) {
    // ============ P1: stage encoder states -> arena; AE encoders (fp64) ============
    {
      // arena[k][a*8+s8] <- arr[a][k*GS + 8Q + s8]  (own 8 samples, all 4 arrays)
#pragma unroll
      for (int i = 0; i < 2; i++) {
        const int pp = 2 * t + i, k = pp >> 2, aidx = pp & 3;
        const float* src = (aidx == 0) ? h0c : (aidx == 1) ? c0c
                         : (aidx == 2) ? h1c : c1c;
        const float4* s4 = (const float4*)(src + (size_t)k * GS + 8 * Q);
        float4* d4 = (float4*)&AK(k, aidx * 8);
        d4[0] = s4[0]; d4[1] = s4[1];
      }
      __syncthreads();
      double a0 = (double)be[n];
      const float* weh = We + n;
#pragma unroll 4
      for (int k = 0; k < HH; k++)
        a0 = fma((double)AK(k, 16 * ae + se), (double)weh[(size_t)k * BNE], a0);
      const float* wec = We + (size_t)HH * BNE + n;
#pragma unroll 4
      for (int k = 0; k < HH; k++)
        a0 = fma((double)AK(k, 16 * ae + 8 + se), (double)wec[(size_t)k * BNE], a0);
      trg[ae * (BNE * GS) + n * GS + sE] =
          (a0 > Athr) ? 1.f : ((a0 < -Athr) ? -1.f : 0.f);
    }
    gbar(cnt, 4 * (++bar));

    // ============ P2: AE decode (column quarter, both AEs) — r4 verbatim ============
    {
      for (int i = t; i < 2 * BNE * GS; i += NTHR) (&tq[0][0][0])[i] = trg[i];
      __syncthreads();
      float ac0[8], ac1[8];
#pragma unroll
      for (int s = 0; s < 8; s++) { ac0[s] = bdv; ac1[s] = bdv; }
      const float* wd = Wd + dcol;
#pragma unroll 2
      for (int j = 0; j < BNE; j++) {
        const float wv = wd[(size_t)j * (2 * HH)];
        const float4 qA0 = *(const float4*)&tq[0][j][8 * sg2];
        const float4 qB0 = *(const float4*)&tq[0][j][8 * sg2 + 4];
        const float4 qA1 = *(const float4*)&tq[1][j][8 * sg2];
        const float4 qB1 = *(const float4*)&tq[1][j][8 * sg2 + 4];
        ac0[0] = fmaf(qA0.x, wv, ac0[0]); ac0[1] = fmaf(qA0.y, wv, ac0[1]);
        ac0[2] = fmaf(qA0.z, wv, ac0[2]); ac0[3] = fmaf(qA0.w, wv, ac0[3]);
        ac0[4] = fmaf(qB0.x, wv, ac0[4]); ac0[5] = fmaf(qB0.y, wv, ac0[5]);
        ac0[6] = fmaf(qB0.z, wv, ac0[6]); ac0[7] = fmaf(qB0.w, wv, ac0[7]);
        ac1[0] = fmaf(qA1.x, wv, ac1[0]); ac1[1] = fmaf(qA1.y, wv, ac1[1]);
        ac1[2] = fmaf(qA1.z, wv, ac1[2]); ac1[3] = fmaf(qA1.w, wv, ac1[3]);
        ac1[4] = fmaf(qB1.x, wv, ac1[4]); ac1[5] = fmaf(qB1.y, wv, ac1[5]);
        ac1[6] = fmaf(qB1.z, wv, ac1[6]); ac1[7] = fmaf(qB1.w, wv, ac1[7]);
      }
      if (cl < 128) {
        const int row = (UQ + cl) * GS + 8 * sg2;
#pragma unroll
        for (int s = 0; s < 8; s++) { h0d[row + s] = ac0[s]; h1d[row + s] = ac1[s]; }
      } else {
#pragma unroll
        for (int s = 0; s < 8; s++) {
          cd[0][cl - 128][8 * sg2 + s] = ac0[s];
          cd[1][cl - 128][8 * sg2 + s] = ac1[s];
        }
      }
    }
    gbar(cnt, 4 * (++bar));

    // ============ P3: layer-0 LSTM (states from arena) ============
    {
      float* sxT = &tq[0][0][0];           // [32 feat][32 samp] overlay (trits dead)
      { int s = t >> 5, f = t & 31;
        float xv;
        if (step >= SEQL && f < OUTD) xv = sog[s * OUTD + f];
        else xv = x[((size_t)(S0 + s) * TOT + step) * FIN + f];
        sxT[f * GS + s] = xv; }
      { // stage full h0d -> arena (flat, same [512][32] layout)
        const float4* s4 = (const float4*)h0d; float4* d4 = (float4*)arena;
#pragma unroll
        for (int i = 0; i < 4; i++) d4[t + i * NTHR] = s4[t + i * NTHR];
      }
      __syncthreads();

      float2 a[8];
#pragma unroll
      for (int s = 0; s < 8; s++) a[s] = bb0;
      const float2* wx = (const float2*)(Wih0 + cg);
#pragma unroll 4
      for (int k = 0; k < FIN; k++) {
        const float2 w  = wx[(size_t)k * (G4 / 2)];
        const float4 hA = *(const float4*)&sxT[k * GS + 8 * v];
        const float4 hB = *(const float4*)&sxT[k * GS + 8 * v + 4];
        MACQ(hA, hB);
      }
      const float2* wh = (const float2*)(Whh0 + cg);
#pragma unroll 8
      for (int k = 0; k < HH; k++) {
        const float2 w  = wh[(size_t)k * (G4 / 2)];
        const float4 hA = *(const float4*)&AK(k, 8 * v);
        const float4 hB = *(const float4*)&AK(k, 8 * v + 4);
        MACQ(hA, hB);
      }
      __syncthreads();   // arena (h0d) dead -> reuse as gate buffer
#pragma unroll
      for (int s = 0; s < 8; s++)
        *(float2*)&GB(8 * v + s, p * 128 + 2 * wl) = a[s];
      __syncthreads();
      // elementwise: 128 units x 32 samples (r4 verbatim)
#pragma unroll
      for (int i = 0; i < 4; i++) {
        const int s = sq8 * 4 + i;
        const float ig = sigf(GB(s, ul));
        const float fg = sigf(GB(s, 128 + ul));
        const float gt = tanhf(GB(s, 256 + ul));
        const float og = sigf(GB(s, 384 + ul));
        const float c2 = fmaf(fg, cd[0][ul][s], ig * gt);
        h0c[(UQ + ul) * GS + s] = og * tanhf(c2);
        c0c[(UQ + ul) * GS + s] = c2;
      }
    }
    gbar(cnt, 4 * (++bar));

    // ============ P4: layer-1 LSTM (staged h0c, then staged h1d) ============
    {
      { // stage full h0c -> arena
        const float4* s4 = (const float4*)h0c; float4* d4 = (float4*)arena;
#pragma unroll
        for (int i = 0; i < 4; i++) d4[t + i * NTHR] = s4[t + i * NTHR];
      }
      __syncthreads();
      float2 a[8];
#pragma unroll
      for (int s = 0; s < 8; s++) a[s] = bb1;
      const float2* wx = (const float2*)(Wih1 + cg);
#pragma unroll 8
      for (int k = 0; k < HH; k++) {
        const float2 w  = wx[(size_t)k * (G4 / 2)];
        const float4 hA = *(const float4*)&AK(k, 8 * v);
        const float4 hB = *(const float4*)&AK(k, 8 * v + 4);
        MACQ(hA, hB);
      }
      __syncthreads();   // arena (h0c) dead
      { // stage full h1d -> arena
        const float4* s4 = (const float4*)h1d; float4* d4 = (float4*)arena;
#pragma unroll
        for (int i = 0; i < 4; i++) d4[t + i * NTHR] = s4[t + i * NTHR];
      }
      __syncthreads();
      const float2* wh = (const float2*)(Whh1 + cg);
#pragma unroll 8
      for (int k = 0; k < HH; k++) {
        const float2 w  = wh[(size_t)k * (G4 / 2)];
        const float4 hA = *(const float4*)&AK(k, 8 * v);
        const float4 hB = *(const float4*)&AK(k, 8 * v + 4);
        MACQ(hA, hB);
      }
      __syncthreads();   // arena (h1d) dead -> gate buffer
#pragma unroll
      for (int s = 0; s < 8; s++)
        *(float2*)&GB(8 * v + s, p * 128 + 2 * wl) = a[s];
      __syncthreads();
#pragma unroll
      for (int i = 0; i < 4; i++) {
        const int s = sq8 * 4 + i;
        const float ig = sigf(GB(s, ul));
        const float fg = sigf(GB(s, 128 + ul));
        const float gt = tanhf(GB(s, 256 + ul));
        const float og = sigf(GB(s, 384 + ul));
        const float c2 = fmaf(fg, cd[1][ul][s], ig * gt);
        h1c[(UQ + ul) * GS + s] = og * tanhf(c2);
        c1c[(UQ + ul) * GS + s] = c2;
      }
    }
    gbar(cnt, 4 * (++bar));

    // ============ P5: final dense (WG's own 8 samples) — r4 verbatim ============
    if (step >= SEQL - 1) {
      if (t < 8 * OUTD) {
        const int s8 = t >> 3, o = t & 7;
        const int sl = 8 * Q + s8;
        float acc = bf[o];
#pragma unroll 4
        for (int k = 0; k < HH; k++)
          acc = fmaf(h1c[k * GS + sl], Wf[k * OUTD + o], acc);
        sog[sl * OUTD + o] = acc;
        const int slot = step - (SEQL - 1);
        out[((size_t)(S0 + sl) * (1 + LOOK) + slot) * OUTD + o] = acc;
      }
    }
  }
#undef AK
#undef GB
}

extern "C" void kernel_launch(void* const* d_in, const int* in_sizes, int n_in,
                              void* d_out, int out_size, void* d_ws, size_t ws_size,
                              hipStream_t stream) {
  const float* x    = (const float*)d_in[0];
  const float* Wih0 = (const float*)d_in[1];
  const float* Whh0 = (const float*)d_in[2];
  const float* bih0 = (const float*)d_in[3];
  const float* bhh0 = (const float*)d_in[4];
  const float* Wih1 = (const float*)d_in[5];
  const float* Whh1 = (const float*)d_in[6];
  const float* bih1 = (const float*)d_in[7];
  const float* bhh1 = (const float*)d_in[8];
  const float* We   = (const float*)d_in[9];
  const float* be   = (const float*)d_in[10];
  const float* Wd   = (const float*)d_in[11];
  const float* bd   = (const float*)d_in[12];
  const float* Wf   = (const float*)d_in[13];
  const float* bf   = (const float*)d_in[14];

  // zero group counters + initial states (h0,c0,h1,c1) every launch
  hipMemsetAsync(d_ws, 0, (size_t)(WS_ST + 4 * ST_SZ) * sizeof(float), stream);

  fused_rnn<<<NWG, NTHR, 0, stream>>>(x, Wih0, Whh0, bih0, bhh0,
                                      Wih1, Whh1, bih1, bhh1,
                                      We, be, Wd, bd, Wf, bf,
                                      (float*)d_out, (float*)d_ws);
}

// Round 11
// 113437.000 us; speedup vs baseline: 1.5215x; 1.5215x over previous
//
#include <hip/hip_runtime.h>
#include <math.h>

#define NB    2048
#define FIN   32
#define HH    512
#define G4    2048           // 4*H
#define BNE   64
#define OUTD  8
#define SEQL  128
#define LOOK  32
#define TOT   (SEQL + LOOK)
#define TB    8              // samples per workgroup
#define NTHR  1024

__device__ __forceinline__ float sigf(float v) { return 1.0f / (1.0f + expf(-v)); }

// 4 cols (W.xyzw) x 4 samples (HV.xyzw): 16 FMAs
#define FMA4x4(W, HV)                                   \
  { acc[0].x = fmaf((W).x, (HV).x, acc[0].x);           \
    acc[0].y = fmaf((W).y, (HV).x, acc[0].y);           \
    acc[0].z = fmaf((W).z, (HV).x, acc[0].z);           \
    acc[0].w = fmaf((W).w, (HV).x, acc[0].w);           \
    acc[1].x = fmaf((W).x, (HV).y, acc[1].x);           \
    acc[1].y = fmaf((W).y, (HV).y, acc[1].y);           \
    acc[1].z = fmaf((W).z, (HV).y, acc[1].z);           \
    acc[1].w = fmaf((W).w, (HV).y, acc[1].w);           \
    acc[2].x = fmaf((W).x, (HV).z, acc[2].x);           \
    acc[2].y = fmaf((W).y, (HV).z, acc[2].y);           \
    acc[2].z = fmaf((W).z, (HV).z, acc[2].z);           \
    acc[2].w = fmaf((W).w, (HV).z, acc[2].w);           \
    acc[3].x = fmaf((W).x, (HV).w, acc[3].x);           \
    acc[3].y = fmaf((W).y, (HV).w, acc[3].y);           \
    acc[3].z = fmaf((W).z, (HV).w, acc[3].z);           \
    acc[3].w = fmaf((W).w, (HV).w, acc[3].w); }

// issue 8 weight rows (float4 each) of block KB
#define LOADBLK(DST, WP, KB)                            \
  { _Pragma("unroll")                                   \
    for (int i = 0; i < 8; i++)                         \
      DST[i] = (WP)[((KB) * 8 + i) * (G4 / 4)]; }

// consume block KB against 8 state rows
#define FMABLK(SRC, KB, STATE)                          \
  { _Pragma("unroll")                                   \
    for (int i = 0; i < 8; i++) {                       \
      const float4 hv = *(const float4*)&STATE[(KB) * 8 + i][4 * v]; \
      FMA4x4(SRC[i], hv);                               \
    } }

// K=512 loop, 64 blocks, two-block rolling pipeline (8 loads in flight)
#define K512_PIPE(WPTR, STATE)                          \
  { const float4* wp = (const float4*)(WPTR) + q;       \
    float4 wa[8], wb[8];                                \
    LOADBLK(wa, wp, 0)                                  \
    _Pragma("unroll 1")                                 \
    for (int kb = 0; kb < 31; kb++) {                   \
      LOADBLK(wb, wp, 2 * kb + 1)                       \
      FMABLK(wa, 2 * kb, STATE)                         \
      LOADBLK(wa, wp, 2 * kb + 2)                       \
      FMABLK(wb, 2 * kb + 1, STATE)                     \
    }                                                   \
    LOADBLK(wb, wp, 63)                                 \
    FMABLK(wa, 62, STATE)                               \
    FMABLK(wb, 63, STATE) }

__global__ __launch_bounds__(NTHR, 4)
void fused_rnn(const float* __restrict__ x,
               const float* __restrict__ Wih0, const float* __restrict__ Whh0,
               const float* __restrict__ bih0, const float* __restrict__ bhh0,
               const float* __restrict__ Wih1, const float* __restrict__ Whh1,
               const float* __restrict__ bih1, const float* __restrict__ bhh1,
               const float* __restrict__ We,   const float* __restrict__ be,
               const float* __restrict__ Wd,   const float* __restrict__ bd,
               const float* __restrict__ Wf,   const float* __restrict__ bf,
               float* __restrict__ out)
{
  // states transposed [k][sample]: fixed-k access is a wave-uniform float4 broadcast
  __shared__ float sh0[HH][TB], sc0[HH][TB], sh1[HH][TB], sc1[HH][TB];  // 64 KB
  __shared__ float sg[TB][G4];       // gate pre-activations [sample][col], 64 KB
  __shared__ float sq[2][BNE][TB];   // trits [ae][j][sample], 4 KB
  __shared__ float sx[FIN][TB];      // staged x_t, transposed, 1 KB
  __shared__ float sout[TB][OUTD];   // last dense output (AR feedback)

  const int t  = threadIdx.x;          // 0..1023
  const int b0 = blockIdx.x * TB;      // first sample of this WG

  for (int i = t; i < HH * TB; i += NTHR) {
    (&sh0[0][0])[i] = 0.f; (&sc0[0][0])[i] = 0.f;
    (&sh1[0][0])[i] = 0.f; (&sc1[0][0])[i] = 0.f;
  }

  // matmul mapping: thread owns cols [4q, 4q+4) for samples [4v, 4v+4)
  const int q = t & 511, v = t >> 9;
  float4 bg0, bg1;
  { const float4 a = *(const float4*)&bih0[4 * q];
    const float4 b = *(const float4*)&bhh0[4 * q];
    bg0 = make_float4(a.x + b.x, a.y + b.y, a.z + b.z, a.w + b.w); }
  { const float4 a = *(const float4*)&bih1[4 * q];
    const float4 b = *(const float4*)&bhh1[4 * q];
    bg1 = make_float4(a.x + b.x, a.y + b.y, a.z + b.z, a.w + b.w); }

  const double Athr = 0.5493061443340549;  // atanh(0.5): round(tanh(u)) threshold

  for (int step = 0; step < TOT; ++step) {
    __syncthreads();

    // ---------------- Phase A: encode both AEs (fp64, 1 bottleneck unit/thread) ----
    {
      const int ae = t >> 9, s = (t >> 6) & 7, n = t & 63;
      const float* Sh = ae ? &sh1[0][0] : &sh0[0][0];
      const float* Sc = ae ? &sc1[0][0] : &sc0[0][0];
      double a0 = (double)be[n];
      const float* we0 = We + n;
#pragma unroll 4
      for (int k = 0; k < HH; k++)
        a0 = fma((double)Sh[k * TB + s], (double)we0[(size_t)k * BNE], a0);
      const float* we1 = We + (size_t)HH * BNE + n;
#pragma unroll 4
      for (int k = 0; k < HH; k++)
        a0 = fma((double)Sc[k * TB + s], (double)we1[(size_t)k * BNE], a0);
      sq[ae][n][s] = (a0 > Athr) ? 1.f : ((a0 < -Athr) ? -1.f : 0.f);
    }
    __syncthreads();

    // ---------------- Phase B: decode both AEs (1 col/thread) -> states; stage x_t --
    {
      float aq0[TB], aq1[TB];
      const float bdv = bd[t];
#pragma unroll
      for (int s = 0; s < TB; s++) { aq0[s] = bdv; aq1[s] = bdv; }
      const float* wd = Wd + t;          // col t, row stride 1024
#pragma unroll 2
      for (int j = 0; j < BNE; j++) {
        const float w = wd[(size_t)j * (2 * HH)];
        const float4 qA0 = *(const float4*)&sq[0][j][0];
        const float4 qB0 = *(const float4*)&sq[0][j][4];
        const float4 qA1 = *(const float4*)&sq[1][j][0];
        const float4 qB1 = *(const float4*)&sq[1][j][4];
        aq0[0] = fmaf(qA0.x, w, aq0[0]); aq0[1] = fmaf(qA0.y, w, aq0[1]);
        aq0[2] = fmaf(qA0.z, w, aq0[2]); aq0[3] = fmaf(qA0.w, w, aq0[3]);
        aq0[4] = fmaf(qB0.x, w, aq0[4]); aq0[5] = fmaf(qB0.y, w, aq0[5]);
        aq0[6] = fmaf(qB0.z, w, aq0[6]); aq0[7] = fmaf(qB0.w, w, aq0[7]);
        aq1[0] = fmaf(qA1.x, w, aq1[0]); aq1[1] = fmaf(qA1.y, w, aq1[1]);
        aq1[2] = fmaf(qA1.z, w, aq1[2]); aq1[3] = fmaf(qA1.w, w, aq1[3]);
        aq1[4] = fmaf(qB1.x, w, aq1[4]); aq1[5] = fmaf(qB1.y, w, aq1[5]);
        aq1[6] = fmaf(qB1.z, w, aq1[6]); aq1[7] = fmaf(qB1.w, w, aq1[7]);
      }
      if (t < HH) {
#pragma unroll
        for (int s = 0; s < TB; s++) { sh0[t][s] = aq0[s]; sh1[t][s] = aq1[s]; }
      } else {
        const int c = t - HH;
#pragma unroll
        for (int s = 0; s < TB; s++) { sc0[c][s] = aq0[s]; sc1[c][s] = aq1[s]; }
      }
      if (t < FIN * TB) {   // 256 threads stage x_t (with AR feedback)
        int s = t >> 5, f = t & 31;
        float xv;
        if (step >= SEQL && f < OUTD) xv = sout[s][f];
        else xv = x[((size_t)(b0 + s) * TOT + step) * FIN + f];
        sx[f][s] = xv;
      }
    }
    __syncthreads();

    // ---------------- Phase C: layer-0 matmul (4 cols x 4 samples, 8-deep pipe) ----
    {
      float4 acc[4];
      acc[0] = bg0; acc[1] = bg0; acc[2] = bg0; acc[3] = bg0;
      { // x part, K=32: 4 blocks
        const float4* wp = (const float4*)Wih0 + q;
        float4 wa[8], wb[8];
        LOADBLK(wa, wp, 0)
        LOADBLK(wb, wp, 1)
        FMABLK(wa, 0, sx)
        LOADBLK(wa, wp, 2)
        FMABLK(wb, 1, sx)
        LOADBLK(wb, wp, 3)
        FMABLK(wa, 2, sx)
        FMABLK(wb, 3, sx)
      }
      K512_PIPE(Whh0, sh0)
#pragma unroll
      for (int s = 0; s < 4; s++) *(float4*)&sg[4 * v + s][4 * q] = acc[s];
    }
    __syncthreads();
    // layer-0 elementwise: unit h = t&511, 4 samples per thread
    {
      const int h  = t & (HH - 1);
      const int sb = (t >> 9) * 4;
#pragma unroll
      for (int s2 = 0; s2 < 4; s2++) {
        const int s = sb + s2;
        const float ig = sigf(sg[s][h]);
        const float fg = sigf(sg[s][HH + h]);
        const float gt = tanhf(sg[s][2 * HH + h]);
        const float og = sigf(sg[s][3 * HH + h]);
        const float c2 = fmaf(fg, sc0[h][s], ig * gt);
        sc0[h][s] = c2;
        sh0[h][s] = og * tanhf(c2);
      }
    }
    __syncthreads();

    // ---------------- Phase D: layer-1 matmul ----------------
    {
      float4 acc[4];
      acc[0] = bg1; acc[1] = bg1; acc[2] = bg1; acc[3] = bg1;
      K512_PIPE(Wih1, sh0)    // input = new h0
      K512_PIPE(Whh1, sh1)    // recurrent = decoded h1
#pragma unroll
      for (int s = 0; s < 4; s++) *(float4*)&sg[4 * v + s][4 * q] = acc[s];
    }
    __syncthreads();
    // layer-1 elementwise
    {
      const int h  = t & (HH - 1);
      const int sb = (t >> 9) * 4;
#pragma unroll
      for (int s2 = 0; s2 < 4; s2++) {
        const int s = sb + s2;
        const float ig = sigf(sg[s][h]);
        const float fg = sigf(sg[s][HH + h]);
        const float gt = tanhf(sg[s][2 * HH + h]);
        const float og = sigf(sg[s][3 * HH + h]);
        const float c2 = fmaf(fg, sc1[h][s], ig * gt);
        sc1[h][s] = c2;
        sh1[h][s] = og * tanhf(c2);
      }
    }

    // ---------------- Phase E: final dense (warm-up end + every AR step) ----------
    if (step >= SEQL - 1) {
      __syncthreads();  // new sh1 visible
      if (t < TB * OUTD) {
        int s = t >> 3, o = t & 7;
        float a = bf[o];
#pragma unroll 4
        for (int k = 0; k < HH; k++) a = fmaf(sh1[k][s], Wf[k * OUTD + o], a);
        sout[s][o] = a;
        int slot = step - (SEQL - 1);                 // 0..32
        out[((size_t)(b0 + s) * (1 + LOOK) + slot) * OUTD + o] = a;
      }
    }
  }
}

extern "C" void kernel_launch(void* const* d_in, const int* in_sizes, int n_in,
                              void* d_out, int out_size, void* d_ws, size_t ws_size,
                              hipStream_t stream) {
  const float* x    = (const float*)d_in[0];
  const float* Wih0 = (const float*)d_in[1];
  const float* Whh0 = (const float*)d_in[2];
  const float* bih0 = (const float*)d_in[3];
  const float* bhh0 = (const float*)d_in[4];
  const float* Wih1 = (const float*)d_in[5];
  const float* Whh1 = (const float*)d_in[6];
  const float* bih1 = (const float*)d_in[7];
  const float* bhh1 = (const float*)d_in[8];
  const float* We   = (const float*)d_in[9];
  const float* be   = (const float*)d_in[10];
  const float* Wd   = (const float*)d_in[11];
  const float* bd   = (const float*)d_in[12];
  const float* Wf   = (const float*)d_in[13];
  const float* bf   = (const float*)d_in[14];

  fused_rnn<<<NB / TB, NTHR, 0, stream>>>(x, Wih0, Whh0, bih0, bhh0,
                                          Wih1, Whh1, bih1, bhh1,
                                          We, be, Wd, bd, Wf, bf,
                                          (float*)d_out);
}